// Round 5
// baseline (255.991 us; speedup 1.0000x reference)
//
#include <hip/hip_runtime.h>
#include <hip/hip_bf16.h>

#define HW 3136
#define NB 16

typedef float f32x4 __attribute__((ext_vector_type(4)));
typedef short short8 __attribute__((ext_vector_type(8)));
typedef unsigned short ushort8 __attribute__((ext_vector_type(8)));

__device__ inline unsigned short bfb(float f) {
  union { __hip_bfloat16 h; unsigned short u; } cv;
  cv.h = __float2bfloat16(f);
  return cv.u;
}
__device__ inline unsigned pack2(float lo, float hi) {
  return (unsigned)bfb(lo) | ((unsigned)bfb(hi) << 16);
}
// order-preserving float<->uint encode for atomicMax
__device__ inline unsigned fenc(float f) {
  unsigned u = __float_as_uint(f);
  return (u & 0x80000000u) ? ~u : (u | 0x80000000u);
}
__device__ inline float fdec(unsigned e) {
  return (e & 0x80000000u) ? __uint_as_float(e & 0x7FFFFFFFu) : __uint_as_float(~e);
}
__device__ inline float bf2f(unsigned short u) {
  return __uint_as_float((unsigned)u << 16);
}

// ---------------- K0: convert W to bf16, zero pool buffers ----------------
__global__ __launch_bounds__(256) void k0_init(const float* __restrict__ conv_w,
                                               unsigned short* __restrict__ Wbf,
                                               float* __restrict__ psum,
                                               unsigned* __restrict__ pmaxe) {
  int i = blockIdx.x * 256 + threadIdx.x;
  Wbf[i] = bfb(conv_w[i]);
  if (i < 4096) psum[i] = 0.f;
  else if (i < 8192) pmaxe[i - 4096] = 0u;
}

// ---------------- K1: conv1x1 + bias + GELU -> h ; fused channel pooling ----------------
__global__ __launch_bounds__(256) void k1_conv_gelu_pool(
    const float* __restrict__ x, const unsigned short* __restrict__ Wbf,
    const float* __restrict__ conv_b, float* __restrict__ h_out,
    float* __restrict__ psum, unsigned* __restrict__ pmaxe)
{
  __shared__ __align__(16) unsigned short Bs[64 * 264];
  const int bid = blockIdx.x;
  const int b = bid / 49, tile = bid - 49 * (bid / 49);
  const int hw0 = tile * 64;
  const int t = threadIdx.x;

  {
    int g = t & 127, half = t >> 7;
    const float* p0 = x + ((size_t)(b * 256 + 2 * g)) * HW + hw0 + half * 32;
    const float* p1 = p0 + HW;
    unsigned* Bd = (unsigned*)Bs;
#pragma unroll
    for (int i = 0; i < 32; i += 4) {
      float4 a4 = *(const float4*)(p0 + i);
      float4 c4 = *(const float4*)(p1 + i);
      int hw = half * 32 + i;
      Bd[(hw + 0) * 132 + g] = pack2(a4.x, c4.x);
      Bd[(hw + 1) * 132 + g] = pack2(a4.y, c4.y);
      Bd[(hw + 2) * 132 + g] = pack2(a4.z, c4.z);
      Bd[(hw + 3) * 132 + g] = pack2(a4.w, c4.w);
    }
  }
  __syncthreads();

  const int w = t >> 6, l = t & 63, hq = l & 15, g2 = l >> 4;
  const int wm0 = w * 64;
  const f32x4 vzero = {0.f, 0.f, 0.f, 0.f};
  f32x4 acc[4][4];
#pragma unroll
  for (int mi = 0; mi < 4; ++mi)
#pragma unroll
    for (int ni = 0; ni < 4; ++ni) acc[mi][ni] = vzero;

#pragma unroll
  for (int ks = 0; ks < 8; ++ks) {
    short8 a[4], bv[4];
#pragma unroll
    for (int mi = 0; mi < 4; ++mi)
      a[mi] = *(const short8*)(Wbf + (size_t)(wm0 + mi * 16 + hq) * 256 + ks * 32 + g2 * 8);
#pragma unroll
    for (int ni = 0; ni < 4; ++ni)
      bv[ni] = *(const short8*)(Bs + (ni * 16 + hq) * 264 + ks * 32 + g2 * 8);
#pragma unroll
    for (int mi = 0; mi < 4; ++mi)
#pragma unroll
      for (int ni = 0; ni < 4; ++ni)
        acc[mi][ni] = __builtin_amdgcn_mfma_f32_16x16x32_bf16(a[mi], bv[ni], acc[mi][ni], 0, 0, 0);
  }

#pragma unroll
  for (int mi = 0; mi < 4; ++mi) {
#pragma unroll
    for (int r = 0; r < 4; ++r) {
      int o = wm0 + mi * 16 + g2 * 4 + r;
      float bias = conv_b[o];
      float v[4];
#pragma unroll
      for (int ni = 0; ni < 4; ++ni) {
        float s = acc[mi][ni][r] + bias;
        v[ni] = 0.5f * s * (1.0f + erff(s * 0.70710678118654752f));
      }
      float* hp = h_out + ((size_t)(b * 256 + o)) * HW + hw0;
      hp[0 * 16 + hq] = v[0];
      hp[1 * 16 + hq] = v[1];
      hp[2 * 16 + hq] = v[2];
      hp[3 * 16 + hq] = v[3];
      float sm = v[0] + v[1] + v[2] + v[3];
      float mx = fmaxf(fmaxf(v[0], v[1]), fmaxf(v[2], v[3]));
#pragma unroll
      for (int d = 1; d < 16; d <<= 1) {
        sm += __shfl_xor(sm, d);
        mx = fmaxf(mx, __shfl_xor(mx, d));
      }
      if (hq == 0) {
        atomicAdd(psum + b * 256 + o, sm);
        atomicMax(pmaxe + b * 256 + o, fenc(mx));
      }
    }
  }
}

// ---------------- K2: channel attention FCs ----------------
__global__ __launch_bounds__(256) void k2_att(
    const float* __restrict__ psum, const unsigned* __restrict__ pmaxe,
    const float* __restrict__ fc1_w, const float* __restrict__ fc1_b,
    const float* __restrict__ fc2_w, const float* __restrict__ fc2_b,
    float* __restrict__ att)
{
  int b = blockIdx.x, t = threadIdx.x;
  __shared__ float hA[64], hM[64];
  if (t < 128) {
    int j = t & 63;
    bool ism = t >= 64;
    float s = fc1_b[j];
    for (int c = 0; c < 256; ++c) {
      float p = ism ? fdec(pmaxe[b * 256 + c]) : (psum[b * 256 + c] * (1.f / 3136.f));
      s += p * fc1_w[j * 256 + c];
    }
    s = fmaxf(s, 0.f);
    if (ism) hM[j] = s; else hA[j] = s;
  }
  __syncthreads();
  float s1 = fc2_b[t], s2 = s1;
  for (int j = 0; j < 64; ++j) {
    float wv = fc2_w[t * 64 + j];
    s1 += hA[j] * wv;
    s2 += hM[j] * wv;
  }
  att[b * 256 + t] = 1.f / (1.f + expf(-s1)) + 1.f / (1.f + expf(-s2));
}

// ---------------- K34 v4: fused depthwise chain, one plane per block ----------------
// LDS ~31.5KB -> 5 blocks/CU (20 waves):
//   B0h bf16 [4480]: P0 halo h [60][60] (3600 u16); after P1 barrier rewritten as
//       x_init bf16 [56][80] (data cols 12..67, pads 0) -- 16B-aligned rows
//   T1/T2/T3 bf16 row-major [62|66|76][56], vertical pad rows zeroed once
// Tasks: P1/P2/PB: 392 col tasks (8 rows x 1 col); PA: 392 row tasks (1 row x 8 cols)
// x_init (fp32) lives in registers xv0/xv1 between P1 and PB (same task mapping).
__global__ __launch_bounds__(256) void k34_dw(
    const float* __restrict__ h_in, const float* __restrict__ att,
    const float* __restrict__ w5, const float* __restrict__ b5,
    const float* __restrict__ w1x7, const float* __restrict__ b1x7,
    const float* __restrict__ w7x1, const float* __restrict__ b7x1,
    const float* __restrict__ w1x11, const float* __restrict__ b1x11,
    const float* __restrict__ w11x1, const float* __restrict__ b11x1,
    const float* __restrict__ w1x21, const float* __restrict__ b1x21,
    const float* __restrict__ w21x1, const float* __restrict__ b21x1,
    float* __restrict__ xs_out)
{
  __shared__ __align__(16) unsigned short B0h[4480];
  __shared__ __align__(16) unsigned short T1[62 * 56];  // r = y+3
  __shared__ __align__(16) unsigned short T2[66 * 56];  // r = y+5
  __shared__ __align__(16) unsigned short T3[76 * 56];  // r = y+10
  __shared__ __align__(16) float wk5a[25];
  __shared__ __align__(16) float wk[78]; // [0,7)w1x7 [7,14)w7x1 [14,25)w1x11 [25,36)w11x1 [36,57)w1x21 [57,78)w21x1

  const int bid = blockIdx.x;
  const int b = bid >> 8, c = bid & 255;
  const int t = threadIdx.x;
  const size_t plane = (size_t)(b * 256 + c) * HW;
  const float a = att[b * 256 + c];

  if (t < 25) wk5a[t] = w5[c * 25 + t] * a;   // fold channel attention into dw5x5 weights
  if (t >= 32 && t < 110) {
    int k = t - 32;
    float v;
    if (k < 7) v = w1x7[c * 7 + k];
    else if (k < 14) v = w7x1[c * 7 + k - 7];
    else if (k < 25) v = w1x11[c * 11 + k - 14];
    else if (k < 36) v = w11x1[c * 11 + k - 25];
    else if (k < 57) v = w1x21[c * 21 + k - 36];
    else v = w21x1[c * 21 + k - 57];
    wk[k] = v;
  }
  { // zero vertical pad rows of T1/T2/T3 (once; PA never writes them)
    unsigned* T1d = (unsigned*)T1; unsigned* T2d = (unsigned*)T2; unsigned* T3d = (unsigned*)T3;
    for (int i = t; i < 1008; i += 256) {
      if (i < 84) T1d[i] = 0;                       // rows 0..2
      else if (i < 168) T1d[1652 + i - 84] = 0;     // rows 59..61
      else if (i < 308) T2d[i - 168] = 0;           // rows 0..4
      else if (i < 448) T2d[1708 + i - 308] = 0;    // rows 61..65
      else if (i < 728) T3d[i - 448] = 0;           // rows 0..9
      else T3d[1848 + i - 728] = 0;                 // rows 66..75
    }
  }
  { // P0: stage halo'd raw h (rows/cols -2..57) into B0h[60][60] as bf16
    const float* hp = h_in + plane;
    for (int idx = t; idx < 3600; idx += 256) {
      int ly = idx / 60, lx = idx - ly * 60;
      int gy = ly - 2, gx = lx - 2;
      float v = 0.f;
      if ((unsigned)gy < 56u && (unsigned)gx < 56u) v = hp[gy * 56 + gx];
      B0h[idx] = bfb(v);
    }
  }
  __syncthreads();

  // P1: dw5x5 -> registers (fp32 acc from bf16 inputs). 392 tasks, 2 static rounds.
  float xv0[8], xv1[8];
  const float bias5 = b5[c];
  {
    int tau = t, yq = tau / 56, xx = tau - yq * 56, y0 = yq * 8;
    float accv[8];
#pragma unroll
    for (int d = 0; d < 8; ++d) accv[d] = bias5;
#pragma unroll
    for (int kx = 0; kx < 5; ++kx) {
      float col[12];
#pragma unroll
      for (int ry = 0; ry < 12; ++ry) col[ry] = bf2f(B0h[(y0 + ry) * 60 + xx + kx]);
#pragma unroll
      for (int ky = 0; ky < 5; ++ky) {
        float wv = wk5a[ky * 5 + kx];
#pragma unroll
        for (int d = 0; d < 8; ++d) accv[d] += col[d + ky] * wv;
      }
    }
#pragma unroll
    for (int d = 0; d < 8; ++d) xv0[d] = accv[d];
  }
  if (t < 136) {
    int tau = t + 256, yq = tau / 56, xx = tau - yq * 56, y0 = yq * 8;
    float accv[8];
#pragma unroll
    for (int d = 0; d < 8; ++d) accv[d] = bias5;
#pragma unroll
    for (int kx = 0; kx < 5; ++kx) {
      float col[12];
#pragma unroll
      for (int ry = 0; ry < 12; ++ry) col[ry] = bf2f(B0h[(y0 + ry) * 60 + xx + kx]);
#pragma unroll
      for (int ky = 0; ky < 5; ++ky) {
        float wv = wk5a[ky * 5 + kx];
#pragma unroll
        for (int d = 0; d < 8; ++d) accv[d] += col[d + ky] * wv;
      }
    }
#pragma unroll
    for (int d = 0; d < 8; ++d) xv1[d] = accv[d];
  }
  __syncthreads();

  // P2: rewrite B0h as padded x_init bf16 [56][80] (data at col+12), zero col pads
  {
    int tau = t, yq = tau / 56, xx = tau - yq * 56, y0 = yq * 8;
#pragma unroll
    for (int d = 0; d < 8; ++d) B0h[(y0 + d) * 80 + 12 + xx] = bfb(xv0[d]);
  }
  if (t < 136) {
    int tau = t + 256, yq = tau / 56, xx = tau - yq * 56, y0 = yq * 8;
#pragma unroll
    for (int d = 0; d < 8; ++d) B0h[(y0 + d) * 80 + 12 + xx] = bfb(xv1[d]);
  }
  for (int i = t; i < 1344; i += 256) {
    int y = i / 24, j = i - y * 24;
    int lx = (j < 12) ? j : (56 + j);   // pads: cols 0..11 and 68..79 (data at 12..67)
    B0h[y * 80 + lx] = 0;
  }
  __syncthreads();

  // PA: fused horizontal convs. Task = (row y, 8 cols x0..x0+7). win read as 4x b128.
  const float bb1 = b1x7[c], bb2 = b1x11[c], bb3 = b1x21[c];
  {
#pragma unroll
    for (int rnd = 0; rnd < 2; ++rnd) {
      int tau = t + rnd * 256;
      if (rnd == 1 && t >= 136) break;
      int y = tau / 7, x0 = (tau - y * 7) * 8;
      float win[32];
      const unsigned short* rp = B0h + y * 80 + x0;
#pragma unroll
      for (int j = 0; j < 32; j += 8) {
        ushort8 q = *(const ushort8*)(rp + j);
#pragma unroll
        for (int e = 0; e < 8; ++e) win[j + e] = bf2f(q[e]);
      }
      float o1[8], o2[8], o3[8];
#pragma unroll
      for (int d = 0; d < 8; ++d) { o1[d] = bb1; o2[d] = bb2; o3[d] = bb3; }
#pragma unroll
      for (int k = 0; k < 7; ++k) {
        float wv = wk[k];
#pragma unroll
        for (int d = 0; d < 8; ++d) o1[d] += win[d + k + 9] * wv;
      }
#pragma unroll
      for (int k = 0; k < 11; ++k) {
        float wv = wk[14 + k];
#pragma unroll
        for (int d = 0; d < 8; ++d) o2[d] += win[d + k + 7] * wv;
      }
#pragma unroll
      for (int k = 0; k < 21; ++k) {
        float wv = wk[36 + k];
#pragma unroll
        for (int d = 0; d < 8; ++d) o3[d] += win[d + k + 2] * wv;
      }
      uint4 s1, s2, s3;
      s1.x = pack2(o1[0], o1[1]); s1.y = pack2(o1[2], o1[3]); s1.z = pack2(o1[4], o1[5]); s1.w = pack2(o1[6], o1[7]);
      s2.x = pack2(o2[0], o2[1]); s2.y = pack2(o2[2], o2[3]); s2.z = pack2(o2[4], o2[5]); s2.w = pack2(o2[6], o2[7]);
      s3.x = pack2(o3[0], o3[1]); s3.y = pack2(o3[2], o3[3]); s3.z = pack2(o3[4], o3[5]); s3.w = pack2(o3[6], o3[7]);
      *(uint4*)&T1[(y + 3) * 56 + x0] = s1;
      *(uint4*)&T2[(y + 5) * 56 + x0] = s2;
      *(uint4*)&T3[(y + 10) * 56 + x0] = s3;
    }
  }
  __syncthreads();

  // PB: fused vertical convs + x_init add (registers) -> global store
  const float vb = b7x1[c] + b11x1[c] + b21x1[c];
  float* op = xs_out + plane;
  {
    int tau = t, yq = tau / 56, xx = tau - yq * 56, y0 = yq * 8;
    float r8[8];
#pragma unroll
    for (int d = 0; d < 8; ++d) r8[d] = xv0[d] + vb;
    {
      float cw[14];
#pragma unroll
      for (int j = 0; j < 14; ++j) cw[j] = bf2f(T1[(y0 + j) * 56 + xx]);
#pragma unroll
      for (int k = 0; k < 7; ++k) {
        float wv = wk[7 + k];
#pragma unroll
        for (int d = 0; d < 8; ++d) r8[d] += cw[d + k] * wv;
      }
    }
    {
      float cw[18];
#pragma unroll
      for (int j = 0; j < 18; ++j) cw[j] = bf2f(T2[(y0 + j) * 56 + xx]);
#pragma unroll
      for (int k = 0; k < 11; ++k) {
        float wv = wk[25 + k];
#pragma unroll
        for (int d = 0; d < 8; ++d) r8[d] += cw[d + k] * wv;
      }
    }
    {
      float cw[28];
#pragma unroll
      for (int j = 0; j < 28; ++j) cw[j] = bf2f(T3[(y0 + j) * 56 + xx]);
#pragma unroll
      for (int k = 0; k < 21; ++k) {
        float wv = wk[57 + k];
#pragma unroll
        for (int d = 0; d < 8; ++d) r8[d] += cw[d + k] * wv;
      }
    }
#pragma unroll
    for (int d = 0; d < 8; ++d) op[(y0 + d) * 56 + xx] = r8[d];
  }
  if (t < 136) {
    int tau = t + 256, yq = tau / 56, xx = tau - yq * 56, y0 = yq * 8;
    float r8[8];
#pragma unroll
    for (int d = 0; d < 8; ++d) r8[d] = xv1[d] + vb;
    {
      float cw[14];
#pragma unroll
      for (int j = 0; j < 14; ++j) cw[j] = bf2f(T1[(y0 + j) * 56 + xx]);
#pragma unroll
      for (int k = 0; k < 7; ++k) {
        float wv = wk[7 + k];
#pragma unroll
        for (int d = 0; d < 8; ++d) r8[d] += cw[d + k] * wv;
      }
    }
    {
      float cw[18];
#pragma unroll
      for (int j = 0; j < 18; ++j) cw[j] = bf2f(T2[(y0 + j) * 56 + xx]);
#pragma unroll
      for (int k = 0; k < 11; ++k) {
        float wv = wk[25 + k];
#pragma unroll
        for (int d = 0; d < 8; ++d) r8[d] += cw[d + k] * wv;
      }
    }
    {
      float cw[28];
#pragma unroll
      for (int j = 0; j < 28; ++j) cw[j] = bf2f(T3[(y0 + j) * 56 + xx]);
#pragma unroll
      for (int k = 0; k < 21; ++k) {
        float wv = wk[57 + k];
#pragma unroll
        for (int d = 0; d < 8; ++d) r8[d] += cw[d + k] * wv;
      }
    }
#pragma unroll
    for (int d = 0; d < 8; ++d) op[(y0 + d) * 56 + xx] = r8[d];
  }
}

// ---------------- K5: spatial_att = W*xs+b ; out = sa*(att*h) ; result = W*out+b ----------------
__global__ __launch_bounds__(256) void k5_final(
    const float* __restrict__ xs, const unsigned short* __restrict__ Wbf,
    const float* __restrict__ conv_b, const float* __restrict__ att,
    const float* __restrict__ h_in, float* __restrict__ outp)
{
  __shared__ __align__(16) unsigned short Bs[64 * 264];
  const int bid = blockIdx.x;
  const int b = bid / 49, tile = bid - 49 * (bid / 49);
  const int hw0 = tile * 64;
  const int t = threadIdx.x;

  {
    int g = t & 127, half = t >> 7;
    const float* p0 = xs + ((size_t)(b * 256 + 2 * g)) * HW + hw0 + half * 32;
    const float* p1 = p0 + HW;
    unsigned* Bd = (unsigned*)Bs;
#pragma unroll
    for (int i = 0; i < 32; i += 4) {
      float4 a4 = *(const float4*)(p0 + i);
      float4 c4 = *(const float4*)(p1 + i);
      int hw = half * 32 + i;
      Bd[(hw + 0) * 132 + g] = pack2(a4.x, c4.x);
      Bd[(hw + 1) * 132 + g] = pack2(a4.y, c4.y);
      Bd[(hw + 2) * 132 + g] = pack2(a4.z, c4.z);
      Bd[(hw + 3) * 132 + g] = pack2(a4.w, c4.w);
    }
  }
  __syncthreads();

  const int w = t >> 6, l = t & 63, hq = l & 15, g2 = l >> 4;
  const int wm0 = w * 64;
  const f32x4 vzero = {0.f, 0.f, 0.f, 0.f};
  f32x4 acc[4][4];
#pragma unroll
  for (int mi = 0; mi < 4; ++mi)
#pragma unroll
    for (int ni = 0; ni < 4; ++ni) acc[mi][ni] = vzero;

#pragma unroll
  for (int ks = 0; ks < 8; ++ks) {
    short8 a[4], bv[4];
#pragma unroll
    for (int mi = 0; mi < 4; ++mi)
      a[mi] = *(const short8*)(Wbf + (size_t)(wm0 + mi * 16 + hq) * 256 + ks * 32 + g2 * 8);
#pragma unroll
    for (int ni = 0; ni < 4; ++ni)
      bv[ni] = *(const short8*)(Bs + (ni * 16 + hq) * 264 + ks * 32 + g2 * 8);
#pragma unroll
    for (int mi = 0; mi < 4; ++mi)
#pragma unroll
      for (int ni = 0; ni < 4; ++ni)
        acc[mi][ni] = __builtin_amdgcn_mfma_f32_16x16x32_bf16(a[mi], bv[ni], acc[mi][ni], 0, 0, 0);
  }
  __syncthreads();

#pragma unroll
  for (int mi = 0; mi < 4; ++mi) {
#pragma unroll
    for (int r = 0; r < 4; ++r) {
      int o = wm0 + mi * 16 + g2 * 4 + r;
      float bias = conv_b[o];
      float av = att[b * 256 + o];
      const float* hp = h_in + ((size_t)(b * 256 + o)) * HW + hw0;
#pragma unroll
      for (int ni = 0; ni < 4; ++ni) {
        float sa = acc[mi][ni][r] + bias;
        float ov = sa * (av * hp[ni * 16 + hq]);
        Bs[(ni * 16 + hq) * 264 + o] = bfb(ov);
      }
    }
  }
  __syncthreads();

  f32x4 acc2[4][4];
#pragma unroll
  for (int mi = 0; mi < 4; ++mi)
#pragma unroll
    for (int ni = 0; ni < 4; ++ni) acc2[mi][ni] = vzero;
#pragma unroll
  for (int ks = 0; ks < 8; ++ks) {
    short8 a[4], bv[4];
#pragma unroll
    for (int mi = 0; mi < 4; ++mi)
      a[mi] = *(const short8*)(Wbf + (size_t)(wm0 + mi * 16 + hq) * 256 + ks * 32 + g2 * 8);
#pragma unroll
    for (int ni = 0; ni < 4; ++ni)
      bv[ni] = *(const short8*)(Bs + (ni * 16 + hq) * 264 + ks * 32 + g2 * 8);
#pragma unroll
    for (int mi = 0; mi < 4; ++mi)
#pragma unroll
      for (int ni = 0; ni < 4; ++ni)
        acc2[mi][ni] = __builtin_amdgcn_mfma_f32_16x16x32_bf16(a[mi], bv[ni], acc2[mi][ni], 0, 0, 0);
  }

#pragma unroll
  for (int mi = 0; mi < 4; ++mi) {
#pragma unroll
    for (int r = 0; r < 4; ++r) {
      int o = wm0 + mi * 16 + g2 * 4 + r;
      float bias = conv_b[o];
      float* op = outp + ((size_t)(b * 256 + o)) * HW + hw0;
#pragma unroll
      for (int ni = 0; ni < 4; ++ni) op[ni * 16 + hq] = acc2[mi][ni][r] + bias;
    }
  }
}

extern "C" void kernel_launch(void* const* d_in, const int* in_sizes, int n_in,
                              void* d_out, int out_size, void* d_ws, size_t ws_size,
                              hipStream_t stream) {
  const float* x      = (const float*)d_in[0];
  const float* conv_w = (const float*)d_in[1];
  const float* conv_b = (const float*)d_in[2];
  const float* fc1_w  = (const float*)d_in[3];
  const float* fc1_b  = (const float*)d_in[4];
  const float* fc2_w  = (const float*)d_in[5];
  const float* fc2_b  = (const float*)d_in[6];
  const float* w5     = (const float*)d_in[7];
  const float* b5     = (const float*)d_in[8];
  const float* w1x7   = (const float*)d_in[9];
  const float* b1x7   = (const float*)d_in[10];
  const float* w7x1   = (const float*)d_in[11];
  const float* b7x1   = (const float*)d_in[12];
  const float* w1x11  = (const float*)d_in[13];
  const float* b1x11  = (const float*)d_in[14];
  const float* w11x1  = (const float*)d_in[15];
  const float* b11x1  = (const float*)d_in[16];
  const float* w1x21  = (const float*)d_in[17];
  const float* b1x21  = (const float*)d_in[18];
  const float* w21x1  = (const float*)d_in[19];
  const float* b21x1  = (const float*)d_in[20];
  float* out = (float*)d_out;

  char* ws = (char*)d_ws;
  unsigned short* Wbf = (unsigned short*)(ws);            // 131072 B
  float* psum   = (float*)(ws + 131072);                  // 16384 B
  unsigned* pme = (unsigned*)(ws + 147456);               // 16384 B
  float* attb   = (float*)(ws + 163840);                  // 16384 B
  float* xbuf   = (float*)(ws + 180224);                  // 51380224 B (xs)

  k0_init<<<256, 256, 0, stream>>>(conv_w, Wbf, psum, pme);
  k1_conv_gelu_pool<<<784, 256, 0, stream>>>(x, Wbf, conv_b, out, psum, pme);
  k2_att<<<16, 256, 0, stream>>>(psum, pme, fc1_w, fc1_b, fc2_w, fc2_b, attb);
  k34_dw<<<4096, 256, 0, stream>>>(out, attb, w5, b5, w1x7, b1x7, w7x1, b7x1,
                                   w1x11, b1x11, w11x1, b11x1, w1x21, b1x21,
                                   w21x1, b21x1, xbuf);
  k5_final<<<784, 256, 0, stream>>>(xbuf, Wbf, conv_b, attb, out, out);
}

// Round 6
// 252.828 us; speedup vs baseline: 1.0125x; 1.0125x over previous
//
#include <hip/hip_runtime.h>
#include <hip/hip_bf16.h>

#define HW 3136
#define NB 16

typedef float f32x4 __attribute__((ext_vector_type(4)));
typedef short short8 __attribute__((ext_vector_type(8)));

__device__ inline unsigned short bfb(float f) {
  union { __hip_bfloat16 h; unsigned short u; } cv;
  cv.h = __float2bfloat16(f);
  return cv.u;
}
__device__ inline unsigned pack2(float lo, float hi) {
  return (unsigned)bfb(lo) | ((unsigned)bfb(hi) << 16);
}
// order-preserving float<->uint encode for atomicMax
__device__ inline unsigned fenc(float f) {
  unsigned u = __float_as_uint(f);
  return (u & 0x80000000u) ? ~u : (u | 0x80000000u);
}
__device__ inline float fdec(unsigned e) {
  return (e & 0x80000000u) ? __uint_as_float(e & 0x7FFFFFFFu) : __uint_as_float(~e);
}
__device__ inline float bf2f(unsigned short u) {
  return __uint_as_float((unsigned)u << 16);
}

// ---------------- K0: convert W to bf16, zero pool buffers ----------------
__global__ __launch_bounds__(256) void k0_init(const float* __restrict__ conv_w,
                                               unsigned short* __restrict__ Wbf,
                                               float* __restrict__ psum,
                                               unsigned* __restrict__ pmaxe) {
  int i = blockIdx.x * 256 + threadIdx.x;
  Wbf[i] = bfb(conv_w[i]);
  if (i < 4096) psum[i] = 0.f;
  else if (i < 8192) pmaxe[i - 4096] = 0u;
}

// ---------------- K1: conv1x1 + bias + GELU -> h (bf16) ; fused channel pooling ----------------
__global__ __launch_bounds__(256) void k1_conv_gelu_pool(
    const float* __restrict__ x, const unsigned short* __restrict__ Wbf,
    const float* __restrict__ conv_b, unsigned short* __restrict__ h_out,
    float* __restrict__ psum, unsigned* __restrict__ pmaxe)
{
  __shared__ __align__(16) unsigned short Bs[64 * 264];
  const int bid = blockIdx.x;
  const int b = bid / 49, tile = bid - 49 * (bid / 49);
  const int hw0 = tile * 64;
  const int t = threadIdx.x;

  {
    int g = t & 127, half = t >> 7;
    const float* p0 = x + ((size_t)(b * 256 + 2 * g)) * HW + hw0 + half * 32;
    const float* p1 = p0 + HW;
    unsigned* Bd = (unsigned*)Bs;
#pragma unroll
    for (int i = 0; i < 32; i += 4) {
      float4 a4 = *(const float4*)(p0 + i);
      float4 c4 = *(const float4*)(p1 + i);
      int hw = half * 32 + i;
      Bd[(hw + 0) * 132 + g] = pack2(a4.x, c4.x);
      Bd[(hw + 1) * 132 + g] = pack2(a4.y, c4.y);
      Bd[(hw + 2) * 132 + g] = pack2(a4.z, c4.z);
      Bd[(hw + 3) * 132 + g] = pack2(a4.w, c4.w);
    }
  }
  __syncthreads();

  const int w = t >> 6, l = t & 63, hq = l & 15, g2 = l >> 4;
  const int wm0 = w * 64;
  const f32x4 vzero = {0.f, 0.f, 0.f, 0.f};
  f32x4 acc[4][4];
#pragma unroll
  for (int mi = 0; mi < 4; ++mi)
#pragma unroll
    for (int ni = 0; ni < 4; ++ni) acc[mi][ni] = vzero;

#pragma unroll
  for (int ks = 0; ks < 8; ++ks) {
    short8 a[4], bv[4];
#pragma unroll
    for (int mi = 0; mi < 4; ++mi)
      a[mi] = *(const short8*)(Wbf + (size_t)(wm0 + mi * 16 + hq) * 256 + ks * 32 + g2 * 8);
#pragma unroll
    for (int ni = 0; ni < 4; ++ni)
      bv[ni] = *(const short8*)(Bs + (ni * 16 + hq) * 264 + ks * 32 + g2 * 8);
#pragma unroll
    for (int mi = 0; mi < 4; ++mi)
#pragma unroll
      for (int ni = 0; ni < 4; ++ni)
        acc[mi][ni] = __builtin_amdgcn_mfma_f32_16x16x32_bf16(a[mi], bv[ni], acc[mi][ni], 0, 0, 0);
  }

#pragma unroll
  for (int mi = 0; mi < 4; ++mi) {
#pragma unroll
    for (int r = 0; r < 4; ++r) {
      int o = wm0 + mi * 16 + g2 * 4 + r;
      float bias = conv_b[o];
      float v[4];
#pragma unroll
      for (int ni = 0; ni < 4; ++ni) {
        float s = acc[mi][ni][r] + bias;
        v[ni] = 0.5f * s * (1.0f + erff(s * 0.70710678118654752f));
      }
      unsigned short* hp = h_out + ((size_t)(b * 256 + o)) * HW + hw0;
      hp[0 * 16 + hq] = bfb(v[0]);
      hp[1 * 16 + hq] = bfb(v[1]);
      hp[2 * 16 + hq] = bfb(v[2]);
      hp[3 * 16 + hq] = bfb(v[3]);
      float sm = v[0] + v[1] + v[2] + v[3];
      float mx = fmaxf(fmaxf(v[0], v[1]), fmaxf(v[2], v[3]));
#pragma unroll
      for (int d = 1; d < 16; d <<= 1) {
        sm += __shfl_xor(sm, d);
        mx = fmaxf(mx, __shfl_xor(mx, d));
      }
      if (hq == 0) {
        atomicAdd(psum + b * 256 + o, sm);
        atomicMax(pmaxe + b * 256 + o, fenc(mx));
      }
    }
  }
}

// ---------------- K2: channel attention FCs ----------------
__global__ __launch_bounds__(256) void k2_att(
    const float* __restrict__ psum, const unsigned* __restrict__ pmaxe,
    const float* __restrict__ fc1_w, const float* __restrict__ fc1_b,
    const float* __restrict__ fc2_w, const float* __restrict__ fc2_b,
    float* __restrict__ att)
{
  int b = blockIdx.x, t = threadIdx.x;
  __shared__ float hA[64], hM[64];
  if (t < 128) {
    int j = t & 63;
    bool ism = t >= 64;
    float s = fc1_b[j];
    for (int c = 0; c < 256; ++c) {
      float p = ism ? fdec(pmaxe[b * 256 + c]) : (psum[b * 256 + c] * (1.f / 3136.f));
      s += p * fc1_w[j * 256 + c];
    }
    s = fmaxf(s, 0.f);
    if (ism) hM[j] = s; else hA[j] = s;
  }
  __syncthreads();
  float s1 = fc2_b[t], s2 = s1;
  for (int j = 0; j < 64; ++j) {
    float wv = fc2_w[t * 64 + j];
    s1 += hA[j] * wv;
    s2 += hM[j] * wv;
  }
  att[b * 256 + t] = 1.f / (1.f + expf(-s1)) + 1.f / (1.f + expf(-s2));
}

// ---------------- K34 v5: fused depthwise chain, one plane per block ----------------
// LDS ~40.3KB -> 4 blocks/CU:
//   B0 fp32 [4256]: P0 halo h [60][60] (3600 f); after P1 barrier rewritten as
//        x_init fp32 [56][76] (data cols 10..65, pads 0)
//   T1/T2/T3 bf16 row-major [62|66|76][56], vertical pad rows zeroed once
// Tasks: P1/P2/PA: 392 ROW tasks (1 y x 8 cols, x0=8*xq) -> vectorized LDS reads/writes
//        PB: 392 COL tasks (8 rows x 1 col) -> contiguous-lane scalar reads
__global__ __launch_bounds__(256) void k34_dw(
    const unsigned short* __restrict__ h_in, const float* __restrict__ att,
    const float* __restrict__ w5, const float* __restrict__ b5,
    const float* __restrict__ w1x7, const float* __restrict__ b1x7,
    const float* __restrict__ w7x1, const float* __restrict__ b7x1,
    const float* __restrict__ w1x11, const float* __restrict__ b1x11,
    const float* __restrict__ w11x1, const float* __restrict__ b11x1,
    const float* __restrict__ w1x21, const float* __restrict__ b1x21,
    const float* __restrict__ w21x1, const float* __restrict__ b21x1,
    unsigned short* __restrict__ xs_out)
{
  __shared__ __align__(16) float B0[4256];
  __shared__ __align__(16) unsigned short T1[62 * 56];  // r = y+3
  __shared__ __align__(16) unsigned short T2[66 * 56];  // r = y+5
  __shared__ __align__(16) unsigned short T3[76 * 56];  // r = y+10
  __shared__ __align__(16) float wk5a[25];
  __shared__ __align__(16) float wk[78]; // [0,7)w1x7 [7,14)w7x1 [14,25)w1x11 [25,36)w11x1 [36,57)w1x21 [57,78)w21x1

  const int bid = blockIdx.x;
  const int b = bid >> 8, c = bid & 255;
  const int t = threadIdx.x;
  const size_t plane = (size_t)(b * 256 + c) * HW;
  const float a = att[b * 256 + c];

  if (t < 25) wk5a[t] = w5[c * 25 + t] * a;   // fold channel attention into dw5x5 weights
  if (t >= 32 && t < 110) {
    int k = t - 32;
    float v;
    if (k < 7) v = w1x7[c * 7 + k];
    else if (k < 14) v = w7x1[c * 7 + k - 7];
    else if (k < 25) v = w1x11[c * 11 + k - 14];
    else if (k < 36) v = w11x1[c * 11 + k - 25];
    else if (k < 57) v = w1x21[c * 21 + k - 36];
    else v = w21x1[c * 21 + k - 57];
    wk[k] = v;
  }
  { // zero vertical pad rows of T1/T2/T3 (once; PA never writes them)
    unsigned* T1d = (unsigned*)T1; unsigned* T2d = (unsigned*)T2; unsigned* T3d = (unsigned*)T3;
    for (int i = t; i < 1008; i += 256) {
      if (i < 84) T1d[i] = 0;                       // rows 0..2
      else if (i < 168) T1d[1652 + i - 84] = 0;     // rows 59..61
      else if (i < 308) T2d[i - 168] = 0;           // rows 0..4
      else if (i < 448) T2d[1708 + i - 308] = 0;    // rows 61..65
      else if (i < 728) T3d[i - 448] = 0;           // rows 0..9
      else T3d[1848 + i - 728] = 0;                 // rows 66..75
    }
  }
  { // P0: stage halo'd h (rows/cols -2..57) into B0[60][60] fp32 (cvt once here)
    const unsigned short* hp = h_in + plane;
    for (int idx = t; idx < 3600; idx += 256) {
      int ly = idx / 60, lx = idx - ly * 60;
      int gy = ly - 2, gx = lx - 2;
      float v = 0.f;
      if ((unsigned)gy < 56u && (unsigned)gx < 56u) v = bf2f(hp[gy * 56 + gx]);
      B0[idx] = v;
    }
  }
  __syncthreads();

  // P1: dw5x5 -> registers, ROW tasks (y, x0..x0+7), float4 window reads.
  float xr0[8], xr1[8];
  const float bias5 = b5[c];
#pragma unroll
  for (int rnd = 0; rnd < 2; ++rnd) {
    if (rnd == 1 && t >= 136) break;
    int tau = t + rnd * 256;
    int y = tau / 7, x0 = (tau - y * 7) * 8;
    float accv[8];
#pragma unroll
    for (int d = 0; d < 8; ++d) accv[d] = bias5;
#pragma unroll
    for (int ky = 0; ky < 5; ++ky) {
      float col[12];
      const float* rp = B0 + (y + ky) * 60 + x0;
#pragma unroll
      for (int j = 0; j < 12; j += 4) {
        float4 q = *(const float4*)(rp + j);
        col[j] = q.x; col[j + 1] = q.y; col[j + 2] = q.z; col[j + 3] = q.w;
      }
#pragma unroll
      for (int kx = 0; kx < 5; ++kx) {
        float wv = wk5a[ky * 5 + kx];
#pragma unroll
        for (int d = 0; d < 8; ++d) accv[d] += col[kx + d] * wv;
      }
    }
    if (rnd == 0) {
#pragma unroll
      for (int d = 0; d < 8; ++d) xr0[d] = accv[d];
    } else {
#pragma unroll
      for (int d = 0; d < 8; ++d) xr1[d] = accv[d];
    }
  }
  __syncthreads();

  // P2: rewrite B0 as padded x_init fp32 [56][76] (data at col+10), zero col pads.
  // Row writes via aligned float2 ((10+8*xq)*4B % 8 == 0).
#pragma unroll
  for (int rnd = 0; rnd < 2; ++rnd) {
    if (rnd == 1 && t >= 136) break;
    int tau = t + rnd * 256;
    int y = tau / 7, x0 = (tau - y * 7) * 8;
    float* wp = B0 + y * 76 + 10 + x0;
    const float* src = (rnd == 0) ? xr0 : xr1;
#pragma unroll
    for (int j = 0; j < 8; j += 2) {
      float2 q; q.x = src[j]; q.y = src[j + 1];
      *(float2*)(wp + j) = q;
    }
  }
  for (int i = t; i < 1120; i += 256) {
    int y = i / 20, j = i - y * 20;
    int lx = (j < 10) ? j : (56 + j);   // pads: cols 0..9 and 66..75 (data at 10..65)
    B0[y * 76 + lx] = 0.f;
  }
  __syncthreads();

  // PA: fused horizontal convs. ROW task (y, x0..x0+7). win = x_init[y][x0-10..x0+17].
  const float bb1 = b1x7[c], bb2 = b1x11[c], bb3 = b1x21[c];
#pragma unroll
  for (int rnd = 0; rnd < 2; ++rnd) {
    if (rnd == 1 && t >= 136) break;
    int tau = t + rnd * 256;
    int y = tau / 7, x0 = (tau - y * 7) * 8;
    float win[28];
    const float* rp = B0 + y * 76 + x0;
#pragma unroll
    for (int j = 0; j < 28; j += 4) {
      float4 q = *(const float4*)(rp + j);
      win[j] = q.x; win[j + 1] = q.y; win[j + 2] = q.z; win[j + 3] = q.w;
    }
    float o1[8], o2[8], o3[8];
#pragma unroll
    for (int d = 0; d < 8; ++d) { o1[d] = bb1; o2[d] = bb2; o3[d] = bb3; }
#pragma unroll
    for (int k = 0; k < 7; ++k) {
      float wv = wk[k];
#pragma unroll
      for (int d = 0; d < 8; ++d) o1[d] += win[d + k + 7] * wv;
    }
#pragma unroll
    for (int k = 0; k < 11; ++k) {
      float wv = wk[14 + k];
#pragma unroll
      for (int d = 0; d < 8; ++d) o2[d] += win[d + k + 5] * wv;
    }
#pragma unroll
    for (int k = 0; k < 21; ++k) {
      float wv = wk[36 + k];
#pragma unroll
      for (int d = 0; d < 8; ++d) o3[d] += win[d + k] * wv;
    }
    uint4 s1, s2, s3;
    s1.x = pack2(o1[0], o1[1]); s1.y = pack2(o1[2], o1[3]); s1.z = pack2(o1[4], o1[5]); s1.w = pack2(o1[6], o1[7]);
    s2.x = pack2(o2[0], o2[1]); s2.y = pack2(o2[2], o2[3]); s2.z = pack2(o2[4], o2[5]); s2.w = pack2(o2[6], o2[7]);
    s3.x = pack2(o3[0], o3[1]); s3.y = pack2(o3[2], o3[3]); s3.z = pack2(o3[4], o3[5]); s3.w = pack2(o3[6], o3[7]);
    *(uint4*)&T1[(y + 3) * 56 + x0] = s1;
    *(uint4*)&T2[(y + 5) * 56 + x0] = s2;
    *(uint4*)&T3[(y + 10) * 56 + x0] = s3;
  }
  __syncthreads();

  // PB: fused vertical convs + x_init add -> global bf16 store. COL task (8y x 1x).
  const float vb = b7x1[c] + b11x1[c] + b21x1[c];
  unsigned short* op = xs_out + plane;
#pragma unroll
  for (int rnd = 0; rnd < 2; ++rnd) {
    if (rnd == 1 && t >= 136) break;
    int tau = t + rnd * 256;
    int yq = tau / 56, xx = tau - yq * 56, y0 = yq * 8;
    float r8[8];
#pragma unroll
    for (int d = 0; d < 8; ++d) r8[d] = B0[(y0 + d) * 76 + 10 + xx] + vb;
    {
      float cw[14];
#pragma unroll
      for (int j = 0; j < 14; ++j) cw[j] = bf2f(T1[(y0 + j) * 56 + xx]);
#pragma unroll
      for (int k = 0; k < 7; ++k) {
        float wv = wk[7 + k];
#pragma unroll
        for (int d = 0; d < 8; ++d) r8[d] += cw[d + k] * wv;
      }
    }
    {
      float cw[18];
#pragma unroll
      for (int j = 0; j < 18; ++j) cw[j] = bf2f(T2[(y0 + j) * 56 + xx]);
#pragma unroll
      for (int k = 0; k < 11; ++k) {
        float wv = wk[25 + k];
#pragma unroll
        for (int d = 0; d < 8; ++d) r8[d] += cw[d + k] * wv;
      }
    }
    {
      float cw[28];
#pragma unroll
      for (int j = 0; j < 28; ++j) cw[j] = bf2f(T3[(y0 + j) * 56 + xx]);
#pragma unroll
      for (int k = 0; k < 21; ++k) {
        float wv = wk[57 + k];
#pragma unroll
        for (int d = 0; d < 8; ++d) r8[d] += cw[d + k] * wv;
      }
    }
#pragma unroll
    for (int d = 0; d < 8; ++d) op[(y0 + d) * 56 + xx] = bfb(r8[d]);
  }
}

// ---------------- K5: spatial_att = W*xs+b ; out = sa*(att*h) ; result = W*out+b ----------------
__global__ __launch_bounds__(256) void k5_final(
    const unsigned short* __restrict__ xs, const unsigned short* __restrict__ Wbf,
    const float* __restrict__ conv_b, const float* __restrict__ att,
    const unsigned short* __restrict__ h_in, float* __restrict__ outp)
{
  __shared__ __align__(16) unsigned short Bs[64 * 264];
  const int bid = blockIdx.x;
  const int b = bid / 49, tile = bid - 49 * (bid / 49);
  const int hw0 = tile * 64;
  const int t = threadIdx.x;

  { // stage xs (already bf16) transposed into LDS, no converts
    int g = t & 127, half = t >> 7;
    const unsigned short* p0 = xs + ((size_t)(b * 256 + 2 * g)) * HW + hw0 + half * 32;
    const unsigned short* p1 = p0 + HW;
    unsigned* Bd = (unsigned*)Bs;
#pragma unroll
    for (int i = 0; i < 32; i += 4) {
      ushort4 a4 = *(const ushort4*)(p0 + i);
      ushort4 c4 = *(const ushort4*)(p1 + i);
      int hw = half * 32 + i;
      Bd[(hw + 0) * 132 + g] = (unsigned)a4.x | ((unsigned)c4.x << 16);
      Bd[(hw + 1) * 132 + g] = (unsigned)a4.y | ((unsigned)c4.y << 16);
      Bd[(hw + 2) * 132 + g] = (unsigned)a4.z | ((unsigned)c4.z << 16);
      Bd[(hw + 3) * 132 + g] = (unsigned)a4.w | ((unsigned)c4.w << 16);
    }
  }
  __syncthreads();

  const int w = t >> 6, l = t & 63, hq = l & 15, g2 = l >> 4;
  const int wm0 = w * 64;
  const f32x4 vzero = {0.f, 0.f, 0.f, 0.f};
  f32x4 acc[4][4];
#pragma unroll
  for (int mi = 0; mi < 4; ++mi)
#pragma unroll
    for (int ni = 0; ni < 4; ++ni) acc[mi][ni] = vzero;

#pragma unroll
  for (int ks = 0; ks < 8; ++ks) {
    short8 a[4], bv[4];
#pragma unroll
    for (int mi = 0; mi < 4; ++mi)
      a[mi] = *(const short8*)(Wbf + (size_t)(wm0 + mi * 16 + hq) * 256 + ks * 32 + g2 * 8);
#pragma unroll
    for (int ni = 0; ni < 4; ++ni)
      bv[ni] = *(const short8*)(Bs + (ni * 16 + hq) * 264 + ks * 32 + g2 * 8);
#pragma unroll
    for (int mi = 0; mi < 4; ++mi)
#pragma unroll
      for (int ni = 0; ni < 4; ++ni)
        acc[mi][ni] = __builtin_amdgcn_mfma_f32_16x16x32_bf16(a[mi], bv[ni], acc[mi][ni], 0, 0, 0);
  }
  __syncthreads();

#pragma unroll
  for (int mi = 0; mi < 4; ++mi) {
#pragma unroll
    for (int r = 0; r < 4; ++r) {
      int o = wm0 + mi * 16 + g2 * 4 + r;
      float bias = conv_b[o];
      float av = att[b * 256 + o];
      const unsigned short* hp = h_in + ((size_t)(b * 256 + o)) * HW + hw0;
#pragma unroll
      for (int ni = 0; ni < 4; ++ni) {
        float sa = acc[mi][ni][r] + bias;
        float ov = sa * (av * bf2f(hp[ni * 16 + hq]));
        Bs[(ni * 16 + hq) * 264 + o] = bfb(ov);
      }
    }
  }
  __syncthreads();

  f32x4 acc2[4][4];
#pragma unroll
  for (int mi = 0; mi < 4; ++mi)
#pragma unroll
    for (int ni = 0; ni < 4; ++ni) acc2[mi][ni] = vzero;
#pragma unroll
  for (int ks = 0; ks < 8; ++ks) {
    short8 a[4], bv[4];
#pragma unroll
    for (int mi = 0; mi < 4; ++mi)
      a[mi] = *(const short8*)(Wbf + (size_t)(wm0 + mi * 16 + hq) * 256 + ks * 32 + g2 * 8);
#pragma unroll
    for (int ni = 0; ni < 4; ++ni)
      bv[ni] = *(const short8*)(Bs + (ni * 16 + hq) * 264 + ks * 32 + g2 * 8);
#pragma unroll
    for (int mi = 0; mi < 4; ++mi)
#pragma unroll
      for (int ni = 0; ni < 4; ++ni)
        acc2[mi][ni] = __builtin_amdgcn_mfma_f32_16x16x32_bf16(a[mi], bv[ni], acc2[mi][ni], 0, 0, 0);
  }

#pragma unroll
  for (int mi = 0; mi < 4; ++mi) {
#pragma unroll
    for (int r = 0; r < 4; ++r) {
      int o = wm0 + mi * 16 + g2 * 4 + r;
      float bias = conv_b[o];
      float* op = outp + ((size_t)(b * 256 + o)) * HW + hw0;
#pragma unroll
      for (int ni = 0; ni < 4; ++ni) op[ni * 16 + hq] = acc2[mi][ni][r] + bias;
    }
  }
}

extern "C" void kernel_launch(void* const* d_in, const int* in_sizes, int n_in,
                              void* d_out, int out_size, void* d_ws, size_t ws_size,
                              hipStream_t stream) {
  const float* x      = (const float*)d_in[0];
  const float* conv_w = (const float*)d_in[1];
  const float* conv_b = (const float*)d_in[2];
  const float* fc1_w  = (const float*)d_in[3];
  const float* fc1_b  = (const float*)d_in[4];
  const float* fc2_w  = (const float*)d_in[5];
  const float* fc2_b  = (const float*)d_in[6];
  const float* w5     = (const float*)d_in[7];
  const float* b5     = (const float*)d_in[8];
  const float* w1x7   = (const float*)d_in[9];
  const float* b1x7   = (const float*)d_in[10];
  const float* w7x1   = (const float*)d_in[11];
  const float* b7x1   = (const float*)d_in[12];
  const float* w1x11  = (const float*)d_in[13];
  const float* b1x11  = (const float*)d_in[14];
  const float* w11x1  = (const float*)d_in[15];
  const float* b11x1  = (const float*)d_in[16];
  const float* w1x21  = (const float*)d_in[17];
  const float* b1x21  = (const float*)d_in[18];
  const float* w21x1  = (const float*)d_in[19];
  const float* b21x1  = (const float*)d_in[20];
  float* out = (float*)d_out;

  char* ws = (char*)d_ws;
  unsigned short* Wbf = (unsigned short*)(ws);            // 131072 B
  float* psum   = (float*)(ws + 131072);                  // 16384 B
  unsigned* pme = (unsigned*)(ws + 147456);               // 16384 B
  float* attb   = (float*)(ws + 163840);                  // 16384 B
  unsigned short* hbuf = (unsigned short*)(ws + 180224);  // 25690112 B (h bf16)
  unsigned short* xbuf = (unsigned short*)(ws + 180224 + 25690112); // 25690112 B (xs bf16)

  k0_init<<<256, 256, 0, stream>>>(conv_w, Wbf, psum, pme);
  k1_conv_gelu_pool<<<784, 256, 0, stream>>>(x, Wbf, conv_b, hbuf, psum, pme);
  k2_att<<<16, 256, 0, stream>>>(psum, pme, fc1_w, fc1_b, fc2_w, fc2_b, attb);
  k34_dw<<<4096, 256, 0, stream>>>(hbuf, attb, w5, b5, w1x7, b1x7, w7x1, b7x1,
                                   w1x11, b1x11, w11x1, b11x1, w1x21, b1x21,
                                   w21x1, b21x1, xbuf);
  k5_final<<<784, 256, 0, stream>>>(xbuf, Wbf, conv_b, attb, hbuf, out);
}

// Round 7
// 240.370 us; speedup vs baseline: 1.0650x; 1.0518x over previous
//
#include <hip/hip_runtime.h>
#include <hip/hip_bf16.h>

#define HW 3136
#define NB 16

typedef float f32x4 __attribute__((ext_vector_type(4)));
typedef short short8 __attribute__((ext_vector_type(8)));

__device__ inline unsigned short bfb(float f) {
  union { __hip_bfloat16 h; unsigned short u; } cv;
  cv.h = __float2bfloat16(f);
  return cv.u;
}
__device__ inline unsigned pack2(float lo, float hi) {
  return (unsigned)bfb(lo) | ((unsigned)bfb(hi) << 16);
}
// order-preserving float<->uint encode for atomicMax
__device__ inline unsigned fenc(float f) {
  unsigned u = __float_as_uint(f);
  return (u & 0x80000000u) ? ~u : (u | 0x80000000u);
}
__device__ inline float fdec(unsigned e) {
  return (e & 0x80000000u) ? __uint_as_float(e & 0x7FFFFFFFu) : __uint_as_float(~e);
}
__device__ inline float bf2f(unsigned short u) {
  return __uint_as_float((unsigned)u << 16);
}

// ---------------- K0: convert W to bf16, zero pool buffers ----------------
__global__ __launch_bounds__(256) void k0_init(const float* __restrict__ conv_w,
                                               unsigned short* __restrict__ Wbf,
                                               float* __restrict__ psum,
                                               unsigned* __restrict__ pmaxe) {
  int i = blockIdx.x * 256 + threadIdx.x;
  Wbf[i] = bfb(conv_w[i]);
  if (i < 4096) psum[i] = 0.f;
  else if (i < 8192) pmaxe[i - 4096] = 0u;
}

// ---------------- K1: conv1x1 + bias + GELU -> h (bf16) ; fused channel pooling ----------------
__global__ __launch_bounds__(256) void k1_conv_gelu_pool(
    const float* __restrict__ x, const unsigned short* __restrict__ Wbf,
    const float* __restrict__ conv_b, unsigned short* __restrict__ h_out,
    float* __restrict__ psum, unsigned* __restrict__ pmaxe)
{
  __shared__ __align__(16) unsigned short Bs[64 * 264];
  const int bid = blockIdx.x;
  const int b = bid / 49, tile = bid - 49 * (bid / 49);
  const int hw0 = tile * 64;
  const int t = threadIdx.x;

  {
    int g = t & 127, half = t >> 7;
    const float* p0 = x + ((size_t)(b * 256 + 2 * g)) * HW + hw0 + half * 32;
    const float* p1 = p0 + HW;
    unsigned* Bd = (unsigned*)Bs;
#pragma unroll
    for (int i = 0; i < 32; i += 4) {
      float4 a4 = *(const float4*)(p0 + i);
      float4 c4 = *(const float4*)(p1 + i);
      int hw = half * 32 + i;
      Bd[(hw + 0) * 132 + g] = pack2(a4.x, c4.x);
      Bd[(hw + 1) * 132 + g] = pack2(a4.y, c4.y);
      Bd[(hw + 2) * 132 + g] = pack2(a4.z, c4.z);
      Bd[(hw + 3) * 132 + g] = pack2(a4.w, c4.w);
    }
  }
  __syncthreads();

  const int w = t >> 6, l = t & 63, hq = l & 15, g2 = l >> 4;
  const int wm0 = w * 64;
  const f32x4 vzero = {0.f, 0.f, 0.f, 0.f};
  f32x4 acc[4][4];
#pragma unroll
  for (int mi = 0; mi < 4; ++mi)
#pragma unroll
    for (int ni = 0; ni < 4; ++ni) acc[mi][ni] = vzero;

#pragma unroll
  for (int ks = 0; ks < 8; ++ks) {
    short8 a[4], bv[4];
#pragma unroll
    for (int mi = 0; mi < 4; ++mi)
      a[mi] = *(const short8*)(Wbf + (size_t)(wm0 + mi * 16 + hq) * 256 + ks * 32 + g2 * 8);
#pragma unroll
    for (int ni = 0; ni < 4; ++ni)
      bv[ni] = *(const short8*)(Bs + (ni * 16 + hq) * 264 + ks * 32 + g2 * 8);
#pragma unroll
    for (int mi = 0; mi < 4; ++mi)
#pragma unroll
      for (int ni = 0; ni < 4; ++ni)
        acc[mi][ni] = __builtin_amdgcn_mfma_f32_16x16x32_bf16(a[mi], bv[ni], acc[mi][ni], 0, 0, 0);
  }

#pragma unroll
  for (int mi = 0; mi < 4; ++mi) {
#pragma unroll
    for (int r = 0; r < 4; ++r) {
      int o = wm0 + mi * 16 + g2 * 4 + r;
      float bias = conv_b[o];
      float v[4];
#pragma unroll
      for (int ni = 0; ni < 4; ++ni) {
        float s = acc[mi][ni][r] + bias;
        v[ni] = 0.5f * s * (1.0f + erff(s * 0.70710678118654752f));
      }
      unsigned short* hp = h_out + ((size_t)(b * 256 + o)) * HW + hw0;
      hp[0 * 16 + hq] = bfb(v[0]);
      hp[1 * 16 + hq] = bfb(v[1]);
      hp[2 * 16 + hq] = bfb(v[2]);
      hp[3 * 16 + hq] = bfb(v[3]);
      float sm = v[0] + v[1] + v[2] + v[3];
      float mx = fmaxf(fmaxf(v[0], v[1]), fmaxf(v[2], v[3]));
#pragma unroll
      for (int d = 1; d < 16; d <<= 1) {
        sm += __shfl_xor(sm, d);
        mx = fmaxf(mx, __shfl_xor(mx, d));
      }
      if (hq == 0) {
        atomicAdd(psum + b * 256 + o, sm);
        atomicMax(pmaxe + b * 256 + o, fenc(mx));
      }
    }
  }
}

// ---------------- K2: channel attention FCs ----------------
__global__ __launch_bounds__(256) void k2_att(
    const float* __restrict__ psum, const unsigned* __restrict__ pmaxe,
    const float* __restrict__ fc1_w, const float* __restrict__ fc1_b,
    const float* __restrict__ fc2_w, const float* __restrict__ fc2_b,
    float* __restrict__ att)
{
  int b = blockIdx.x, t = threadIdx.x;
  __shared__ float hA[64], hM[64];
  if (t < 128) {
    int j = t & 63;
    bool ism = t >= 64;
    float s = fc1_b[j];
    for (int c = 0; c < 256; ++c) {
      float p = ism ? fdec(pmaxe[b * 256 + c]) : (psum[b * 256 + c] * (1.f / 3136.f));
      s += p * fc1_w[j * 256 + c];
    }
    s = fmaxf(s, 0.f);
    if (ism) hM[j] = s; else hA[j] = s;
  }
  __syncthreads();
  float s1 = fc2_b[t], s2 = s1;
  for (int j = 0; j < 64; ++j) {
    float wv = fc2_w[t * 64 + j];
    s1 += hA[j] * wv;
    s2 += hM[j] * wv;
  }
  att[b * 256 + t] = 1.f / (1.f + expf(-s1)) + 1.f / (1.f + expf(-s2));
}

// ---------------- K34 v6: fused depthwise chain, one plane per block ----------------
// LDS ~40.3KB -> 4 blocks/CU (pinned via __launch_bounds__(256,4)):
//   B0 fp32 [4256]: P0 halo h [60][60]; after P1 barrier rewritten as
//        x_init fp32 [56][76] (data cols 10..65, pads 0)
//   T1/T2/T3 bf16 row-major [62|66|76][56], vertical pad rows zeroed once
// Tasks: P1/P2/PA: 392 ROW tasks (1 y x 8 cols) -> b128 LDS reads/writes
//        PB: 196 COLUMN-PAIR tasks (8 rows x 2 cols) -> b32 packed reads (2 bf16/instr)
__global__ __launch_bounds__(256, 4) void k34_dw(
    const unsigned short* __restrict__ h_in, const float* __restrict__ att,
    const float* __restrict__ w5, const float* __restrict__ b5,
    const float* __restrict__ w1x7, const float* __restrict__ b1x7,
    const float* __restrict__ w7x1, const float* __restrict__ b7x1,
    const float* __restrict__ w1x11, const float* __restrict__ b1x11,
    const float* __restrict__ w11x1, const float* __restrict__ b11x1,
    const float* __restrict__ w1x21, const float* __restrict__ b1x21,
    const float* __restrict__ w21x1, const float* __restrict__ b21x1,
    unsigned short* __restrict__ xs_out)
{
  __shared__ __align__(16) float B0[4256];
  __shared__ __align__(16) unsigned short T1[62 * 56];  // r = y+3
  __shared__ __align__(16) unsigned short T2[66 * 56];  // r = y+5
  __shared__ __align__(16) unsigned short T3[76 * 56];  // r = y+10
  __shared__ __align__(16) float wk5a[25];
  __shared__ __align__(16) float wk[78]; // [0,7)w1x7 [7,14)w7x1 [14,25)w1x11 [25,36)w11x1 [36,57)w1x21 [57,78)w21x1

  const int bid = blockIdx.x;
  const int b = bid >> 8, c = bid & 255;
  const int t = threadIdx.x;
  const size_t plane = (size_t)(b * 256 + c) * HW;
  const float a = att[b * 256 + c];

  if (t < 25) wk5a[t] = w5[c * 25 + t] * a;   // fold channel attention into dw5x5 weights
  if (t >= 32 && t < 110) {
    int k = t - 32;
    float v;
    if (k < 7) v = w1x7[c * 7 + k];
    else if (k < 14) v = w7x1[c * 7 + k - 7];
    else if (k < 25) v = w1x11[c * 11 + k - 14];
    else if (k < 36) v = w11x1[c * 11 + k - 25];
    else if (k < 57) v = w1x21[c * 21 + k - 36];
    else v = w21x1[c * 21 + k - 57];
    wk[k] = v;
  }
  { // zero vertical pad rows of T1/T2/T3 (once; PA never writes them)
    unsigned* T1d = (unsigned*)T1; unsigned* T2d = (unsigned*)T2; unsigned* T3d = (unsigned*)T3;
    for (int i = t; i < 1008; i += 256) {
      if (i < 84) T1d[i] = 0;                       // rows 0..2
      else if (i < 168) T1d[1652 + i - 84] = 0;     // rows 59..61
      else if (i < 308) T2d[i - 168] = 0;           // rows 0..4
      else if (i < 448) T2d[1708 + i - 308] = 0;    // rows 61..65
      else if (i < 728) T3d[i - 448] = 0;           // rows 0..9
      else T3d[1848 + i - 728] = 0;                 // rows 66..75
    }
  }
  { // P0: stage halo'd h (rows/cols -2..57) into B0[60][60] fp32 (cvt once here)
    const unsigned short* hp = h_in + plane;
    for (int idx = t; idx < 3600; idx += 256) {
      int ly = idx / 60, lx = idx - ly * 60;
      int gy = ly - 2, gx = lx - 2;
      float v = 0.f;
      if ((unsigned)gy < 56u && (unsigned)gx < 56u) v = bf2f(hp[gy * 56 + gx]);
      B0[idx] = v;
    }
  }
  __syncthreads();

  // P1: dw5x5 -> registers, ROW tasks (y, x0..x0+7), float4 window reads.
  float xr0[8], xr1[8];
  const float bias5 = b5[c];
#pragma unroll
  for (int rnd = 0; rnd < 2; ++rnd) {
    if (rnd == 1 && t >= 136) break;
    int tau = t + rnd * 256;
    int y = tau / 7, x0 = (tau - y * 7) * 8;
    float accv[8];
#pragma unroll
    for (int d = 0; d < 8; ++d) accv[d] = bias5;
#pragma unroll
    for (int ky = 0; ky < 5; ++ky) {
      float col[12];
      const float* rp = B0 + (y + ky) * 60 + x0;
#pragma unroll
      for (int j = 0; j < 12; j += 4) {
        float4 q = *(const float4*)(rp + j);
        col[j] = q.x; col[j + 1] = q.y; col[j + 2] = q.z; col[j + 3] = q.w;
      }
#pragma unroll
      for (int kx = 0; kx < 5; ++kx) {
        float wv = wk5a[ky * 5 + kx];
#pragma unroll
        for (int d = 0; d < 8; ++d) accv[d] += col[kx + d] * wv;
      }
    }
    if (rnd == 0) {
#pragma unroll
      for (int d = 0; d < 8; ++d) xr0[d] = accv[d];
    } else {
#pragma unroll
      for (int d = 0; d < 8; ++d) xr1[d] = accv[d];
    }
  }
  __syncthreads();

  // P2: rewrite B0 as padded x_init fp32 [56][76] (data at col+10), zero col pads.
#pragma unroll
  for (int rnd = 0; rnd < 2; ++rnd) {
    if (rnd == 1 && t >= 136) break;
    int tau = t + rnd * 256;
    int y = tau / 7, x0 = (tau - y * 7) * 8;
    float* wp = B0 + y * 76 + 10 + x0;
    const float* src = (rnd == 0) ? xr0 : xr1;
#pragma unroll
    for (int j = 0; j < 8; j += 2) {
      float2 q; q.x = src[j]; q.y = src[j + 1];
      *(float2*)(wp + j) = q;
    }
  }
  for (int i = t; i < 1120; i += 256) {
    int y = i / 20, j = i - y * 20;
    int lx = (j < 10) ? j : (56 + j);   // pads: cols 0..9 and 66..75 (data at 10..65)
    B0[y * 76 + lx] = 0.f;
  }
  __syncthreads();

  // PA: fused horizontal convs. ROW task (y, x0..x0+7). win = x_init[y][x0-10..x0+17].
  const float bb1 = b1x7[c], bb2 = b1x11[c], bb3 = b1x21[c];
#pragma unroll
  for (int rnd = 0; rnd < 2; ++rnd) {
    if (rnd == 1 && t >= 136) break;
    int tau = t + rnd * 256;
    int y = tau / 7, x0 = (tau - y * 7) * 8;
    float win[28];
    const float* rp = B0 + y * 76 + x0;
#pragma unroll
    for (int j = 0; j < 28; j += 4) {
      float4 q = *(const float4*)(rp + j);
      win[j] = q.x; win[j + 1] = q.y; win[j + 2] = q.z; win[j + 3] = q.w;
    }
    float o1[8], o2[8], o3[8];
#pragma unroll
    for (int d = 0; d < 8; ++d) { o1[d] = bb1; o2[d] = bb2; o3[d] = bb3; }
#pragma unroll
    for (int k = 0; k < 7; ++k) {
      float wv = wk[k];
#pragma unroll
      for (int d = 0; d < 8; ++d) o1[d] += win[d + k + 7] * wv;
    }
#pragma unroll
    for (int k = 0; k < 11; ++k) {
      float wv = wk[14 + k];
#pragma unroll
      for (int d = 0; d < 8; ++d) o2[d] += win[d + k + 5] * wv;
    }
#pragma unroll
    for (int k = 0; k < 21; ++k) {
      float wv = wk[36 + k];
#pragma unroll
      for (int d = 0; d < 8; ++d) o3[d] += win[d + k] * wv;
    }
    uint4 s1, s2, s3;
    s1.x = pack2(o1[0], o1[1]); s1.y = pack2(o1[2], o1[3]); s1.z = pack2(o1[4], o1[5]); s1.w = pack2(o1[6], o1[7]);
    s2.x = pack2(o2[0], o2[1]); s2.y = pack2(o2[2], o2[3]); s2.z = pack2(o2[4], o2[5]); s2.w = pack2(o2[6], o2[7]);
    s3.x = pack2(o3[0], o3[1]); s3.y = pack2(o3[2], o3[3]); s3.z = pack2(o3[4], o3[5]); s3.w = pack2(o3[6], o3[7]);
    *(uint4*)&T1[(y + 3) * 56 + x0] = s1;
    *(uint4*)&T2[(y + 5) * 56 + x0] = s2;
    *(uint4*)&T3[(y + 10) * 56 + x0] = s3;
  }
  __syncthreads();

  // PB: fused vertical convs + x_init add -> global bf16 store.
  // COLUMN-PAIR task: (8 rows y0..y0+7) x (2 cols x0,x0+1); 196 tasks, 1 round.
  // T reads are packed b32 (2 bf16); unpack via shift/mask (no cvt).
  const float vb = b7x1[c] + b11x1[c] + b21x1[c];
  unsigned short* op = xs_out + plane;
  if (t < 196) {
    int band = t / 28, xp = t - band * 28;
    int y0 = band * 8, x0 = xp * 2;
    float rlo[8], rhi[8];
#pragma unroll
    for (int d = 0; d < 8; ++d) {
      float2 q = *(const float2*)&B0[(y0 + d) * 76 + 10 + x0];
      rlo[d] = q.x + vb; rhi[d] = q.y + vb;
    }
    {
      float clo[14], chi[14];
#pragma unroll
      for (int j = 0; j < 14; ++j) {
        unsigned q = *(const unsigned*)&T1[(y0 + j) * 56 + x0];
        clo[j] = __uint_as_float(q << 16);
        chi[j] = __uint_as_float(q & 0xffff0000u);
      }
#pragma unroll
      for (int k = 0; k < 7; ++k) {
        float wv = wk[7 + k];
#pragma unroll
        for (int d = 0; d < 8; ++d) { rlo[d] += clo[d + k] * wv; rhi[d] += chi[d + k] * wv; }
      }
    }
    {
      float clo[18], chi[18];
#pragma unroll
      for (int j = 0; j < 18; ++j) {
        unsigned q = *(const unsigned*)&T2[(y0 + j) * 56 + x0];
        clo[j] = __uint_as_float(q << 16);
        chi[j] = __uint_as_float(q & 0xffff0000u);
      }
#pragma unroll
      for (int k = 0; k < 11; ++k) {
        float wv = wk[25 + k];
#pragma unroll
        for (int d = 0; d < 8; ++d) { rlo[d] += clo[d + k] * wv; rhi[d] += chi[d + k] * wv; }
      }
    }
    {
      float clo[28], chi[28];
#pragma unroll
      for (int j = 0; j < 28; ++j) {
        unsigned q = *(const unsigned*)&T3[(y0 + j) * 56 + x0];
        clo[j] = __uint_as_float(q << 16);
        chi[j] = __uint_as_float(q & 0xffff0000u);
      }
#pragma unroll
      for (int k = 0; k < 21; ++k) {
        float wv = wk[57 + k];
#pragma unroll
        for (int d = 0; d < 8; ++d) { rlo[d] += clo[d + k] * wv; rhi[d] += chi[d + k] * wv; }
      }
    }
#pragma unroll
    for (int d = 0; d < 8; ++d)
      *(unsigned*)&op[(y0 + d) * 56 + x0] = pack2(rlo[d], rhi[d]);
  }
}

// ---------------- K5: spatial_att = W*xs+b ; out = sa*(att*h) ; result = W*out+b ----------------
__global__ __launch_bounds__(256) void k5_final(
    const unsigned short* __restrict__ xs, const unsigned short* __restrict__ Wbf,
    const float* __restrict__ conv_b, const float* __restrict__ att,
    const unsigned short* __restrict__ h_in, float* __restrict__ outp)
{
  __shared__ __align__(16) unsigned short Bs[64 * 264];
  const int bid = blockIdx.x;
  const int b = bid / 49, tile = bid - 49 * (bid / 49);
  const int hw0 = tile * 64;
  const int t = threadIdx.x;

  { // stage xs (already bf16) transposed into LDS, no converts
    int g = t & 127, half = t >> 7;
    const unsigned short* p0 = xs + ((size_t)(b * 256 + 2 * g)) * HW + hw0 + half * 32;
    const unsigned short* p1 = p0 + HW;
    unsigned* Bd = (unsigned*)Bs;
#pragma unroll
    for (int i = 0; i < 32; i += 4) {
      ushort4 a4 = *(const ushort4*)(p0 + i);
      ushort4 c4 = *(const ushort4*)(p1 + i);
      int hw = half * 32 + i;
      Bd[(hw + 0) * 132 + g] = (unsigned)a4.x | ((unsigned)c4.x << 16);
      Bd[(hw + 1) * 132 + g] = (unsigned)a4.y | ((unsigned)c4.y << 16);
      Bd[(hw + 2) * 132 + g] = (unsigned)a4.z | ((unsigned)c4.z << 16);
      Bd[(hw + 3) * 132 + g] = (unsigned)a4.w | ((unsigned)c4.w << 16);
    }
  }
  __syncthreads();

  const int w = t >> 6, l = t & 63, hq = l & 15, g2 = l >> 4;
  const int wm0 = w * 64;
  const f32x4 vzero = {0.f, 0.f, 0.f, 0.f};
  f32x4 acc[4][4];
#pragma unroll
  for (int mi = 0; mi < 4; ++mi)
#pragma unroll
    for (int ni = 0; ni < 4; ++ni) acc[mi][ni] = vzero;

#pragma unroll
  for (int ks = 0; ks < 8; ++ks) {
    short8 a[4], bv[4];
#pragma unroll
    for (int mi = 0; mi < 4; ++mi)
      a[mi] = *(const short8*)(Wbf + (size_t)(wm0 + mi * 16 + hq) * 256 + ks * 32 + g2 * 8);
#pragma unroll
    for (int ni = 0; ni < 4; ++ni)
      bv[ni] = *(const short8*)(Bs + (ni * 16 + hq) * 264 + ks * 32 + g2 * 8);
#pragma unroll
    for (int mi = 0; mi < 4; ++mi)
#pragma unroll
      for (int ni = 0; ni < 4; ++ni)
        acc[mi][ni] = __builtin_amdgcn_mfma_f32_16x16x32_bf16(a[mi], bv[ni], acc[mi][ni], 0, 0, 0);
  }
  __syncthreads();

#pragma unroll
  for (int mi = 0; mi < 4; ++mi) {
#pragma unroll
    for (int r = 0; r < 4; ++r) {
      int o = wm0 + mi * 16 + g2 * 4 + r;
      float bias = conv_b[o];
      float av = att[b * 256 + o];
      const unsigned short* hp = h_in + ((size_t)(b * 256 + o)) * HW + hw0;
#pragma unroll
      for (int ni = 0; ni < 4; ++ni) {
        float sa = acc[mi][ni][r] + bias;
        float ov = sa * (av * bf2f(hp[ni * 16 + hq]));
        Bs[(ni * 16 + hq) * 264 + o] = bfb(ov);
      }
    }
  }
  __syncthreads();

  f32x4 acc2[4][4];
#pragma unroll
  for (int mi = 0; mi < 4; ++mi)
#pragma unroll
    for (int ni = 0; ni < 4; ++ni) acc2[mi][ni] = vzero;
#pragma unroll
  for (int ks = 0; ks < 8; ++ks) {
    short8 a[4], bv[4];
#pragma unroll
    for (int mi = 0; mi < 4; ++mi)
      a[mi] = *(const short8*)(Wbf + (size_t)(wm0 + mi * 16 + hq) * 256 + ks * 32 + g2 * 8);
#pragma unroll
    for (int ni = 0; ni < 4; ++ni)
      bv[ni] = *(const short8*)(Bs + (ni * 16 + hq) * 264 + ks * 32 + g2 * 8);
#pragma unroll
    for (int mi = 0; mi < 4; ++mi)
#pragma unroll
      for (int ni = 0; ni < 4; ++ni)
        acc2[mi][ni] = __builtin_amdgcn_mfma_f32_16x16x32_bf16(a[mi], bv[ni], acc2[mi][ni], 0, 0, 0);
  }

#pragma unroll
  for (int mi = 0; mi < 4; ++mi) {
#pragma unroll
    for (int r = 0; r < 4; ++r) {
      int o = wm0 + mi * 16 + g2 * 4 + r;
      float bias = conv_b[o];
      float* op = outp + ((size_t)(b * 256 + o)) * HW + hw0;
#pragma unroll
      for (int ni = 0; ni < 4; ++ni) op[ni * 16 + hq] = acc2[mi][ni][r] + bias;
    }
  }
}

extern "C" void kernel_launch(void* const* d_in, const int* in_sizes, int n_in,
                              void* d_out, int out_size, void* d_ws, size_t ws_size,
                              hipStream_t stream) {
  const float* x      = (const float*)d_in[0];
  const float* conv_w = (const float*)d_in[1];
  const float* conv_b = (const float*)d_in[2];
  const float* fc1_w  = (const float*)d_in[3];
  const float* fc1_b  = (const float*)d_in[4];
  const float* fc2_w  = (const float*)d_in[5];
  const float* fc2_b  = (const float*)d_in[6];
  const float* w5     = (const float*)d_in[7];
  const float* b5     = (const float*)d_in[8];
  const float* w1x7   = (const float*)d_in[9];
  const float* b1x7   = (const float*)d_in[10];
  const float* w7x1   = (const float*)d_in[11];
  const float* b7x1   = (const float*)d_in[12];
  const float* w1x11  = (const float*)d_in[13];
  const float* b1x11  = (const float*)d_in[14];
  const float* w11x1  = (const float*)d_in[15];
  const float* b11x1  = (const float*)d_in[16];
  const float* w1x21  = (const float*)d_in[17];
  const float* b1x21  = (const float*)d_in[18];
  const float* w21x1  = (const float*)d_in[19];
  const float* b21x1  = (const float*)d_in[20];
  float* out = (float*)d_out;

  char* ws = (char*)d_ws;
  unsigned short* Wbf = (unsigned short*)(ws);            // 131072 B
  float* psum   = (float*)(ws + 131072);                  // 16384 B
  unsigned* pme = (unsigned*)(ws + 147456);               // 16384 B
  float* attb   = (float*)(ws + 163840);                  // 16384 B
  unsigned short* hbuf = (unsigned short*)(ws + 180224);  // 25690112 B (h bf16)
  unsigned short* xbuf = (unsigned short*)(ws + 180224 + 25690112); // 25690112 B (xs bf16)

  k0_init<<<256, 256, 0, stream>>>(conv_w, Wbf, psum, pme);
  k1_conv_gelu_pool<<<784, 256, 0, stream>>>(x, Wbf, conv_b, hbuf, psum, pme);
  k2_att<<<16, 256, 0, stream>>>(psum, pme, fc1_w, fc1_b, fc2_w, fc2_b, attb);
  k34_dw<<<4096, 256, 0, stream>>>(hbuf, attb, w5, b5, w1x7, b1x7, w7x1, b7x1,
                                   w1x11, b1x11, w11x1, b11x1, w1x21, b1x21,
                                   w21x1, b21x1, xbuf);
  k5_final<<<784, 256, 0, stream>>>(xbuf, Wbf, conv_b, attb, hbuf, out);
}